// Round 16
// baseline (119.850 us; speedup 1.0000x reference)
//
#include <hip/hip_runtime.h>
#include <stdint.h>

#define NPIX 16384
#define IMW 128
#define NIMG 8
#define NLVL 11
#define BIGK 0xFFFFFFFFu
#define IMASK 16383u
#define DONE 0x0D0E0D0Eu   // != 0xAAAAAAAA ws-poison, so flags need no init

// ---------------- key-based union-find (u32 keys in LDS) — r12/r14-verified ----------------
// par[i] holds the KEY ((lvl<<14)|idx) of i's parent; par[i]==key(i) <=> root.
// Values stored at any slot strictly decrease over time (halving installs an
// ancestor's key; CAS replaces hi by lo<hi) -> acyclic, ABA-free, terminates.
__device__ __forceinline__ unsigned findk(volatile unsigned* par, unsigned i) {
    unsigned k = par[i];
    for (;;) {
        unsigned j = k & IMASK;
        unsigned pk = par[j];
        if (pk == k) return k;       // par[j] == key(j) -> j is root
        par[i] = pk;                 // path halving (benign race, ancestor only)
        i = j; k = pk;
    }
}

// elder rule: smaller key survives. Plain 32-bit CAS — fails only on true conflicts.
__device__ __forceinline__ void unionk(volatile unsigned* par, unsigned* par32,
                                       unsigned a, unsigned b) {
    unsigned ka = findk(par, a);
    unsigned kb = findk(par, b);
    while (ka != kb) {
        unsigned hi = max(ka, kb);   // younger root key: absorbed
        unsigned lo = min(ka, kb);   // elder root key: survives
        unsigned hidx = hi & IMASK;
        if (atomicCAS(par32 + hidx, hi, lo) == hi) return;
        ka = findk(par, hidx);
        kb = findk(par, lo & IMASK);
    }
}

__device__ __forceinline__ void flag_release(unsigned* p) {
    __threadfence();
    __hip_atomic_store(p, DONE, __ATOMIC_RELEASE, __HIP_MEMORY_SCOPE_AGENT);
}
__device__ __forceinline__ void flag_acquire(unsigned* p) {
    while (__hip_atomic_load(p, __ATOMIC_ACQUIRE, __HIP_MEMORY_SCOPE_AGENT) != DONE)
        __builtin_amdgcn_s_sleep(2);
}

// ================= dispatch 1: prep (r14-verbatim) — sigmoid cached in LDS ===========
__global__ __launch_bounds__(1024) void prep_kernel(const float* __restrict__ model_output,
                                                    const float* __restrict__ labels,
                                                    uint8_t* __restrict__ lvl_all,
                                                    int* __restrict__ maxL_all,
                                                    unsigned* __restrict__ argmin_all,
                                                    unsigned* __restrict__ rootmask_all)
{
    __shared__ float s_sig[NPIX];   // 64 KB sigmoid cache (pred images)
    __shared__ float s_f[32];
    __shared__ unsigned s_u[32];
    __shared__ float s_mnmx[2];

    int img = blockIdx.x;
    int tid = threadIdx.x;
    unsigned lane = tid & 63u;
    bool ismask = img < 4;
    const float* src = ismask ? (labels + (size_t)img * NPIX)
                              : (model_output + (size_t)(img - 4) * NPIX);
    uint8_t* lvl = lvl_all + (size_t)img * NPIX;
    unsigned* rm = rootmask_all + (size_t)img * NPIX;

    // zero rootmask for this image (ws is poisoned 0xAA)
    for (int q = tid; q < NPIX / 4; q += 1024)
        ((uint4*)rm)[q] = make_uint4(0, 0, 0, 0);

    float mn = 0.f, mx = 1.f;
    if (!ismask) {
        // pass 1: sigmoid -> LDS, min/max in the same sweep (one global read, one expf)
        float lmn = 1e30f, lmx = -1e30f;
        for (int i = tid; i < NPIX; i += 1024) {
            float s = 1.0f / (1.0f + expf(-src[i]));
            s_sig[i] = s;
            lmn = fminf(lmn, s); lmx = fmaxf(lmx, s);
        }
        for (int off = 32; off > 0; off >>= 1) {
            lmn = fminf(lmn, __shfl_down(lmn, off));
            lmx = fmaxf(lmx, __shfl_down(lmx, off));
        }
        int wv = tid >> 6;
        if (lane == 0) { s_f[wv] = lmn; s_f[16 + wv] = lmx; }
        __syncthreads();
        if (tid == 0) {
            float a = s_f[0], c = s_f[16];
            for (int w = 1; w < 16; ++w) { a = fminf(a, s_f[w]); c = fmaxf(c, s_f[16 + w]); }
            s_mnmx[0] = a; s_mnmx[1] = c;
        }
        __syncthreads();
        mn = s_mnmx[0]; mx = s_mnmx[1];
    }
    float denom = mx - mn;
    if (denom <= 0.f) denom = 1.f;

    // pass 2: quantize (LDS-read for preds; identical float arithmetic)
    unsigned lmaxk = 0, bestk = BIGK;
    for (int i = tid; i < NPIX; i += 1024) {
        int L;
        if (ismask) L = (int)rintf(src[i] * 10.0f);
        else        L = (int)rintf((s_sig[i] - mn) / denom * 10.0f);
        lvl[i] = (uint8_t)L;
        unsigned key = ((unsigned)L << 14) | (unsigned)i;
        lmaxk = max(lmaxk, (unsigned)L);
        bestk = min(bestk, key);
    }
    for (int off = 32; off > 0; off >>= 1) {
        lmaxk = max(lmaxk, (unsigned)__shfl_down((int)lmaxk, off));
        bestk = min(bestk, (unsigned)__shfl_down((int)bestk, off));
    }
    if (lane == 0) { s_u[tid >> 6] = lmaxk; s_u[16 + (tid >> 6)] = bestk; }
    __syncthreads();
    if (tid == 0) {
        unsigned m = s_u[0], b = s_u[16];
        for (int w = 1; w < 16; ++w) { m = max(m, s_u[w]); b = min(b, s_u[16 + w]); }
        maxL_all[img] = (int)m;
        argmin_all[img] = b & IMASK;
    }
}

// ========== dispatch 2: 88 ccl + 8 death + 1 wdist = 97 blocks ==========
// r15 structure; one change: two pointer-jumping compression sweeps between
// Phase B1 and B2 to flatten find chains before the cross-strip merge.
__global__ __launch_bounds__(1024) void ccl_death_wdist(const uint8_t* __restrict__ lvl_all,
                                                        const int* __restrict__ maxL_all,
                                                        const unsigned* __restrict__ argmin_all,
                                                        unsigned* __restrict__ rootmask_all,
                                                        float* __restrict__ outP,
                                                        float* __restrict__ outB,
                                                        float* __restrict__ outD,
                                                        unsigned* __restrict__ flags,
                                                        unsigned* __restrict__ dflags,
                                                        float* __restrict__ out)
{
    __shared__ __align__(16) unsigned char smem[65536];
    int blk = blockIdx.x;
    int tid = threadIdx.x;
    unsigned lane = tid & 63u;

    if (blk < 88) {
        // ================= ccl =================
        int b = blk;
        int img = b / NLVL, l = b % NLVL;
        int w = tid >> 6;                  // wave id == 8-row strip id
        const uint8_t* lv = lvl_all + (size_t)img * NPIX;
        unsigned* rm = rootmask_all + (size_t)img * NPIX;
        unsigned* s_par = (unsigned*)smem;          // 64 KB
        volatile unsigned* par = s_par;
        int maxL = maxL_all[img];

        if (l >= maxL) {   // whole grid one component: single root = argmin
            if (tid == 0) {
                atomicOr(&rm[argmin_all[img]], 1u << l);
                flag_release(&flags[b]);
            }
            return;
        }

        // Phase A: horizontal runs -> par = run min-KEY (ballot + seg scan).
        // i = w*1024 + k*64 + lane; each (w,k) is one 64-px segment (rows = 2 segs).
        // Inactive pixels store their own true key (level > l) as inactivity marker.
        unsigned am = 0;
#pragma unroll
        for (int k = 0; k < 16; ++k) {
            int i = (w << 10) + (k << 6) + (int)lane;
            unsigned Lv = lv[i];
            bool act = (int)Lv <= l;
            if (act) am |= 1u << k;
            unsigned key = (Lv << 14) | (unsigned)i;
            unsigned long long m = __ballot(act);
            unsigned kv = act ? key : BIGK;
            unsigned long long lowmask = (1ull << lane) - 1ull;
            unsigned long long zb = (~m) & lowmask;
            int runstart = zb ? (64 - __clzll(zb)) : 0;
            unsigned v = kv;
#pragma unroll
            for (int d = 1; d < 64; d <<= 1) {
                unsigned o = __shfl_up(v, d, 64);
                if ((int)lane - d >= runstart) v = min(v, o);
            }
            unsigned long long za = (lane == 63u) ? 0ull : ((~m) >> (lane + 1));
            int runend = za ? ((int)lane + __ffsll((long long)za) - 1) : 63;
            unsigned rmin = __shfl(v, runend, 64);
            s_par[i] = act ? rmin : key;
        }

        unsigned amL  = (unsigned)__shfl_up((int)am, 1, 64);   // lane-1's mask (junk lane 0)
        unsigned am63 = (unsigned)__shfl((int)am, 63, 64);     // lane 63's mask

        // Phase B1: intra-strip unions (register guards; own-wave LDS only)
#pragma unroll
        for (int k = 0; k < 16; ++k) {
            if (!((am >> k) & 1u)) continue;
            int i = (w << 10) + (k << 6) + (int)lane;
            if ((k & 1) && lane == 0u && ((am63 >> (k - 1)) & 1u))   // seam at col 64
                unionk(par, s_par, (unsigned)i, (unsigned)(i - 1));
            if (k >= 2 && ((am >> (k - 2)) & 1u)) {                  // vertical in strip
                bool leftpair = (lane > 0u) && ((amL >> k) & 1u) && ((amL >> (k - 2)) & 1u);
                if (!leftpair)
                    unionk(par, s_par, (unsigned)i, (unsigned)(i - IMW));
            }
        }
        __syncthreads();

        // ---- NEW: two compression sweeps — flatten B1 trees before cross-strip
        // merge. Installs an ancestor's key only (monotone-safe under races;
        // roots are fixed points), so the UF invariants are preserved.
#pragma unroll
        for (int s = 0; s < 2; ++s) {
#pragma unroll
            for (int k = 0; k < 16; ++k) {
                int i = (w << 10) + (k << 6) + (int)lane;
                unsigned p1 = s_par[i];
                unsigned p2 = s_par[p1 & IMASK];
                unsigned p3 = s_par[p2 & IMASK];
                s_par[i] = p3;
            }
        }
        __syncthreads();

        // Phase B2: inter-strip boundary rows (first row of strips 1..15).
        // Up-neighbor activity from key level field (inactive slots keep level > l).
        if (w >= 1) {
#pragma unroll
            for (int k = 0; k < 2; ++k) {
                if (!((am >> k) & 1u)) continue;
                int i = (w << 10) + (k << 6) + (int)lane;
                if ((int)(s_par[i - IMW] >> 14) <= l) {
                    int col = (k << 6) + (int)lane;
                    bool lact = (lane > 0u) ? (((amL >> k) & 1u) != 0u)
                                            : (k == 1 ? (((am63 >> 0) & 1u) != 0u) : false);
                    bool leftpair = (col != 0) && lact && ((int)(s_par[i - 1 - IMW] >> 14) <= l);
                    if (!leftpair)
                        unionk(par, s_par, (unsigned)i, (unsigned)(i - IMW));
                }
            }
        }
        __syncthreads();

        // emit: root iff active && par[i]'s idx == i (keys are unique per idx)
#pragma unroll
        for (int k = 0; k < 16; ++k) {
            if (!((am >> k) & 1u)) continue;
            int i = (w << 10) + (k << 6) + (int)lane;
            if ((s_par[i] & IMASK) == (unsigned)i) atomicOr(&rm[i], 1u << l);
        }
        __syncthreads();
        if (tid == 0) flag_release(&flags[b]);
        return;
    }

    if (blk < 96) {
        // ================= death (r15-verbatim body) =================
        int img = blk - 88;
        uint8_t*  s_lvl  = (uint8_t*)smem;                               // 16384
        uint8_t*  s_rank = (uint8_t*)(smem + 16384);                     // 16384
        unsigned long long* s_bm = (unsigned long long*)(smem + 32768);  // 2048
        unsigned* s_keys = (unsigned*)(smem + 34816);                    // 1024
        unsigned* s_pc   = (unsigned*)(smem + 35840);                    // 1024
        unsigned* s_hist = (unsigned*)(smem + 36864);                    // 256
        uint8_t*  s_rtab = (uint8_t*)(smem + 37120);                     // 128
        unsigned* s_ctl  = (unsigned*)(smem + 37248);                    // 16

        if (tid < NLVL) flag_acquire(&flags[img * NLVL + tid]);
        __syncthreads();

        const uint8_t* lv = lvl_all + (size_t)img * NPIX;
        const unsigned* rmg = rootmask_all + (size_t)img * NPIX;
        int maxL = maxL_all[img];

        ((uint4*)s_lvl)[tid] = ((const uint4*)lv)[tid];
        if (tid < 64) s_hist[tid] = 0;
        if (tid < 256) { s_bm[tid] = 0ull; s_keys[tid] = 0xFFFFFFFFu; }
        // rank(d,b) = #(of 55 (dd,bb) pairs) with strictly larger f32 pers;
        // order-isomorphic to float ordering; equal floats share rank -> tie by idx.
        if (tid < NLVL * NLVL) {
            int d = tid / NLVL, bb0 = tid % NLVL;
            if (d > bb0) {
                float pers = (float)d / 10.0f - (float)bb0 / 10.0f;
                unsigned rk = 0;
                for (int dd = 1; dd <= 10; ++dd)
                    for (int bb = 0; bb < dd; ++bb) {
                        float pp = (float)dd / 10.0f - (float)bb / 10.0f;
                        rk += (pp > pers) ? 1u : 0u;
                    }
                s_rtab[d * NLVL + bb0] = (uint8_t)rk;
            }
        }
        __syncthreads();

        // pass 1: candidate iff root at birth level; death = first clear bit above b
        for (int i = tid; i < NPIX; i += 1024) {
            uint8_t r = 0xFF;
            int b = s_lvl[i];
            unsigned rmv = rmg[i];
            if ((rmv >> b) & 1u) {
                unsigned inv = (~rmv) >> (b + 1);
                int d = b + 1 + (__ffs(inv) - 1);
                d = min(d, maxL);
                if (d > b) { r = s_rtab[d * NLVL + b]; atomicAdd(&s_hist[r], 1u); }
            }
            s_rank[i] = r;
        }
        __syncthreads();

        if (tid == 0) {
            unsigned cum = 0, rstar = 63, cless = 0;
            for (int r = 0; r < 56; ++r) {
                if (cum + s_hist[r] >= 256u && rstar == 63u) { rstar = r; cless = cum; }
                cum += s_hist[r];
            }
            if (rstar == 63u) cless = cum;
            s_ctl[0] = rstar; s_ctl[1] = cless;
            s_ctl[2] = (rstar == 63u) ? 0u : (256u - cless);
            s_ctl[3] = 0;
        }
        __syncthreads();
        unsigned rstar = s_ctl[0], cless = s_ctl[1], mneed = s_ctl[2];

        // pass 2: compact rank<r*; bitmap for rank==r*
        for (int i = tid; i < NPIX; i += 1024) {
            unsigned r = s_rank[i];
            if (r == 0xFFu) continue;
            if (r < rstar) {
                unsigned pos = atomicAdd(&s_ctl[3], 1u);
                if (pos < 256u) s_keys[pos] = (r << 14) | (unsigned)i;
            } else if (r == rstar) {
                atomicOr(&s_bm[i >> 6], 1ull << (i & 63));
            }
        }
        __syncthreads();

        // bitonic sort 256 keys ascending == (rank asc, idx asc)
        for (unsigned kk = 2; kk <= 256; kk <<= 1) {
            for (unsigned j = kk >> 1; j > 0; j >>= 1) {
                if (tid < 256) {
                    unsigned i = (unsigned)tid, ixj = i ^ j;
                    if (ixj > i) {
                        unsigned x = s_keys[i], y = s_keys[ixj];
                        bool up = ((i & kk) == 0);
                        if ((x > y) == up) { s_keys[i] = y; s_keys[ixj] = x; }
                    }
                }
                __syncthreads();
            }
        }

        // bucket r*: popcount-prefix -> each member computes its slot
        if (tid < 256) s_pc[tid] = (unsigned)__popcll(s_bm[tid]);
        __syncthreads();
        for (int d = 1; d < 256; d <<= 1) {
            unsigned x = 0;
            if (tid < 256 && tid >= d) x = s_pc[tid - d];
            __syncthreads();
            if (tid < 256 && tid >= d) s_pc[tid] += x;
            __syncthreads();
        }
        for (int i = tid; i < NPIX; i += 1024) {
            if (s_rank[i] != rstar || rstar == 63u) continue;
            if (!((s_bm[i >> 6] >> (i & 63)) & 1ull)) continue;
            unsigned w = i >> 6;
            unsigned order = (w ? s_pc[w - 1] : 0u)
                           + (unsigned)__popcll(s_bm[w] & ((1ull << (i & 63)) - 1ull));
            if (order < mneed) s_keys[cless + order] = (rstar << 14) | (unsigned)i;
        }
        __syncthreads();

        for (int s = tid; s < 256; s += 1024) {
            unsigned key = s_keys[s];
            float p = 0.f, bv = 0.f, dv = 0.f;
            if (key != 0xFFFFFFFFu) {
                unsigned i = key & IMASK;
                int b = s_lvl[i];
                unsigned rmv = rmg[i];
                unsigned inv = (~rmv) >> (b + 1);
                int d = b + 1 + (__ffs(inv) - 1);
                d = min(d, maxL);
                bv = (float)b / 10.0f;
                dv = (float)d / 10.0f;
                p = dv - bv;
            }
            outP[img * 256 + s] = p;
            outB[img * 256 + s] = bv;
            outD[img * 256 + s] = dv;
        }
        __syncthreads();
        if (tid == 0) flag_release(&dflags[img]);
        return;
    }

    // ================= wdist (r15-verbatim body) =================
    {
        if (tid < 8) flag_acquire(&dflags[tid]);
        __syncthreads();

        float* part = (float*)smem;          // [16]
        float* dist = (float*)(smem + 64);   // [4]
        int s = tid >> 8;
        int slot = tid & 255;
        int mi = s * 256 + slot;
        int pi = (4 + s) * 256 + slot;
        float p1 = outP[mi], b1 = outB[mi], d1 = outD[mi];
        float p2 = outP[pi], b2 = outB[pi], d2 = outD[pi];
        bool h1 = p1 > 0.f, h2 = p2 > 0.f;
        float cost = 0.f;
        if (h1 && h2)      cost = (b1 - b2) * (b1 - b2) + (d1 - d2) * (d1 - d2);
        else if (h1)       cost = p1 * p1 * 0.5f;
        else if (h2)       cost = p2 * p2 * 0.5f;

        for (int off = 32; off > 0; off >>= 1) cost += __shfl_down(cost, off);
        int wv = tid >> 6;
        if (lane == 0u) part[wv] = cost;
        __syncthreads();
        if (tid < 4) {
            float sum = part[tid * 4] + part[tid * 4 + 1] + part[tid * 4 + 2] + part[tid * 4 + 3];
            dist[tid] = sqrtf(sum + 1e-12f);
        }
        __syncthreads();
        if (tid == 0)
            out[0] = 0.01f * (dist[0] + dist[1] + dist[2] + dist[3]) / 4.0f;
    }
}

// ws layout (bytes):
//   lvl   u8 [8][16384]         @ 0        (131072)
//   maxL  i32[8]                @ 131072   (32)
//   argmin u32[8]               @ 131104   (32)
//   rootmask u32[8][16384]      @ 131136   (524288)
//   outP/outB/outD f32[8][256]  @ 655424   (24576)
//   flags u32[88]               @ 680000   (352)
//   dflags u32[8]               @ 680352   (32)
extern "C" void kernel_launch(void* const* d_in, const int* in_sizes, int n_in,
                              void* d_out, int out_size, void* d_ws, size_t ws_size,
                              hipStream_t stream)
{
    const float* model_output = (const float*)d_in[0];
    const float* labels = (const float*)d_in[1];
    char* ws = (char*)d_ws;
    uint8_t* lvl = (uint8_t*)ws;
    int* maxL = (int*)(ws + 131072);
    unsigned* argmin = (unsigned*)(ws + 131104);
    unsigned* rootmask = (unsigned*)(ws + 131136);
    float* outP = (float*)(ws + 655424);
    float* outB = outP + NIMG * 256;
    float* outD = outB + NIMG * 256;
    unsigned* flags = (unsigned*)(ws + 680000);
    unsigned* dflags = (unsigned*)(ws + 680352);
    float* out = (float*)d_out;

    prep_kernel<<<NIMG, 1024, 0, stream>>>(model_output, labels, lvl, maxL, argmin, rootmask);
    ccl_death_wdist<<<97, 1024, 0, stream>>>(lvl, maxL, argmin, rootmask,
                                             outP, outB, outD, flags, dflags, out);
}

// Round 17
// 117.969 us; speedup vs baseline: 1.0159x; 1.0159x over previous
//
#include <hip/hip_runtime.h>
#include <stdint.h>

#define NPIX 16384
#define IMW 128
#define NIMG 8
#define NLVL 11
#define BIGK 0xFFFFFFFFu
#define IMASK 16383u
#define DONE 0x0D0E0D0Eu   // != 0xAAAAAAAA ws-poison, so flags need no init

// ---------------- key-based union-find (u32 keys in LDS) — r12/r14-verified ----------------
// par[i] holds the KEY ((lvl<<14)|idx) of i's parent; par[i]==key(i) <=> root.
// Values stored at any slot strictly decrease over time (halving installs an
// ancestor's key; CAS replaces hi by lo<hi) -> acyclic, ABA-free, terminates.
__device__ __forceinline__ unsigned findk(volatile unsigned* par, unsigned i) {
    unsigned k = par[i];
    for (;;) {
        unsigned j = k & IMASK;
        unsigned pk = par[j];
        if (pk == k) return k;       // par[j] == key(j) -> j is root
        par[i] = pk;                 // path halving (benign race, ancestor only)
        i = j; k = pk;
    }
}

// elder rule: smaller key survives. Plain 32-bit CAS — fails only on true conflicts.
__device__ __forceinline__ void unionk(volatile unsigned* par, unsigned* par32,
                                       unsigned a, unsigned b) {
    unsigned ka = findk(par, a);
    unsigned kb = findk(par, b);
    while (ka != kb) {
        unsigned hi = max(ka, kb);   // younger root key: absorbed
        unsigned lo = min(ka, kb);   // elder root key: survives
        unsigned hidx = hi & IMASK;
        if (atomicCAS(par32 + hidx, hi, lo) == hi) return;
        ka = findk(par, hidx);
        kb = findk(par, lo & IMASK);
    }
}

__device__ __forceinline__ void flag_release(unsigned* p) {
    __threadfence();
    __hip_atomic_store(p, DONE, __ATOMIC_RELEASE, __HIP_MEMORY_SCOPE_AGENT);
}
__device__ __forceinline__ void flag_acquire(unsigned* p) {
    while (__hip_atomic_load(p, __ATOMIC_ACQUIRE, __HIP_MEMORY_SCOPE_AGENT) != DONE)
        __builtin_amdgcn_s_sleep(2);
}

// ================= dispatch 1: prep (r14-verbatim) — sigmoid cached in LDS ===========
__global__ __launch_bounds__(1024) void prep_kernel(const float* __restrict__ model_output,
                                                    const float* __restrict__ labels,
                                                    uint8_t* __restrict__ lvl_all,
                                                    int* __restrict__ maxL_all,
                                                    unsigned* __restrict__ argmin_all,
                                                    unsigned* __restrict__ rootmask_all)
{
    __shared__ float s_sig[NPIX];   // 64 KB sigmoid cache (pred images)
    __shared__ float s_f[32];
    __shared__ unsigned s_u[32];
    __shared__ float s_mnmx[2];

    int img = blockIdx.x;
    int tid = threadIdx.x;
    unsigned lane = tid & 63u;
    bool ismask = img < 4;
    const float* src = ismask ? (labels + (size_t)img * NPIX)
                              : (model_output + (size_t)(img - 4) * NPIX);
    uint8_t* lvl = lvl_all + (size_t)img * NPIX;
    unsigned* rm = rootmask_all + (size_t)img * NPIX;

    // zero rootmask for this image (ws is poisoned 0xAA)
    for (int q = tid; q < NPIX / 4; q += 1024)
        ((uint4*)rm)[q] = make_uint4(0, 0, 0, 0);

    float mn = 0.f, mx = 1.f;
    if (!ismask) {
        // pass 1: sigmoid -> LDS, min/max in the same sweep (one global read, one expf)
        float lmn = 1e30f, lmx = -1e30f;
        for (int i = tid; i < NPIX; i += 1024) {
            float s = 1.0f / (1.0f + expf(-src[i]));
            s_sig[i] = s;
            lmn = fminf(lmn, s); lmx = fmaxf(lmx, s);
        }
        for (int off = 32; off > 0; off >>= 1) {
            lmn = fminf(lmn, __shfl_down(lmn, off));
            lmx = fmaxf(lmx, __shfl_down(lmx, off));
        }
        int wv = tid >> 6;
        if (lane == 0) { s_f[wv] = lmn; s_f[16 + wv] = lmx; }
        __syncthreads();
        if (tid == 0) {
            float a = s_f[0], c = s_f[16];
            for (int w = 1; w < 16; ++w) { a = fminf(a, s_f[w]); c = fmaxf(c, s_f[16 + w]); }
            s_mnmx[0] = a; s_mnmx[1] = c;
        }
        __syncthreads();
        mn = s_mnmx[0]; mx = s_mnmx[1];
    }
    float denom = mx - mn;
    if (denom <= 0.f) denom = 1.f;

    // pass 2: quantize (LDS-read for preds; identical float arithmetic)
    unsigned lmaxk = 0, bestk = BIGK;
    for (int i = tid; i < NPIX; i += 1024) {
        int L;
        if (ismask) L = (int)rintf(src[i] * 10.0f);
        else        L = (int)rintf((s_sig[i] - mn) / denom * 10.0f);
        lvl[i] = (uint8_t)L;
        unsigned key = ((unsigned)L << 14) | (unsigned)i;
        lmaxk = max(lmaxk, (unsigned)L);
        bestk = min(bestk, key);
    }
    for (int off = 32; off > 0; off >>= 1) {
        lmaxk = max(lmaxk, (unsigned)__shfl_down((int)lmaxk, off));
        bestk = min(bestk, (unsigned)__shfl_down((int)bestk, off));
    }
    if (lane == 0) { s_u[tid >> 6] = lmaxk; s_u[16 + (tid >> 6)] = bestk; }
    __syncthreads();
    if (tid == 0) {
        unsigned m = s_u[0], b = s_u[16];
        for (int w = 1; w < 16; ++w) { m = max(m, s_u[w]); b = min(b, s_u[16 + w]); }
        maxL_all[img] = (int)m;
        argmin_all[img] = b & IMASK;
    }
}

// ========== dispatch 2: 88 ccl + 8 death + 1 wdist = 97 blocks (r15-verbatim) ==========
// flags[0..87]: ccl[(img,l)] done.  dflags[0..7]: death[img] done.
// Producers have lower block IDs; 97 blocks all co-resident.
__global__ __launch_bounds__(1024) void ccl_death_wdist(const uint8_t* __restrict__ lvl_all,
                                                        const int* __restrict__ maxL_all,
                                                        const unsigned* __restrict__ argmin_all,
                                                        unsigned* __restrict__ rootmask_all,
                                                        float* __restrict__ outP,
                                                        float* __restrict__ outB,
                                                        float* __restrict__ outD,
                                                        unsigned* __restrict__ flags,
                                                        unsigned* __restrict__ dflags,
                                                        float* __restrict__ out)
{
    __shared__ __align__(16) unsigned char smem[65536];
    int blk = blockIdx.x;
    int tid = threadIdx.x;
    unsigned lane = tid & 63u;

    if (blk < 88) {
        // ================= ccl =================
        int b = blk;
        int img = b / NLVL, l = b % NLVL;
        int w = tid >> 6;                  // wave id == 8-row strip id
        const uint8_t* lv = lvl_all + (size_t)img * NPIX;
        unsigned* rm = rootmask_all + (size_t)img * NPIX;
        unsigned* s_par = (unsigned*)smem;          // 64 KB
        volatile unsigned* par = s_par;
        int maxL = maxL_all[img];

        if (l >= maxL) {   // whole grid one component: single root = argmin
            if (tid == 0) {
                atomicOr(&rm[argmin_all[img]], 1u << l);
                flag_release(&flags[b]);
            }
            return;
        }

        // Phase A: horizontal runs -> par = run min-KEY (ballot + seg scan).
        // i = w*1024 + k*64 + lane; each (w,k) is one 64-px segment (rows = 2 segs).
        // Inactive pixels store their own true key (level > l) as inactivity marker.
        unsigned am = 0;
#pragma unroll
        for (int k = 0; k < 16; ++k) {
            int i = (w << 10) + (k << 6) + (int)lane;
            unsigned Lv = lv[i];
            bool act = (int)Lv <= l;
            if (act) am |= 1u << k;
            unsigned key = (Lv << 14) | (unsigned)i;
            unsigned long long m = __ballot(act);
            unsigned kv = act ? key : BIGK;
            unsigned long long lowmask = (1ull << lane) - 1ull;
            unsigned long long zb = (~m) & lowmask;
            int runstart = zb ? (64 - __clzll(zb)) : 0;
            unsigned v = kv;
#pragma unroll
            for (int d = 1; d < 64; d <<= 1) {
                unsigned o = __shfl_up(v, d, 64);
                if ((int)lane - d >= runstart) v = min(v, o);
            }
            unsigned long long za = (lane == 63u) ? 0ull : ((~m) >> (lane + 1));
            int runend = za ? ((int)lane + __ffsll((long long)za) - 1) : 63;
            unsigned rmin = __shfl(v, runend, 64);
            s_par[i] = act ? rmin : key;
        }

        unsigned amL  = (unsigned)__shfl_up((int)am, 1, 64);   // lane-1's mask (junk lane 0)
        unsigned am63 = (unsigned)__shfl((int)am, 63, 64);     // lane 63's mask

        // Phase B1: intra-strip unions (register guards; own-wave LDS only)
#pragma unroll
        for (int k = 0; k < 16; ++k) {
            if (!((am >> k) & 1u)) continue;
            int i = (w << 10) + (k << 6) + (int)lane;
            if ((k & 1) && lane == 0u && ((am63 >> (k - 1)) & 1u))   // seam at col 64
                unionk(par, s_par, (unsigned)i, (unsigned)(i - 1));
            if (k >= 2 && ((am >> (k - 2)) & 1u)) {                  // vertical in strip
                bool leftpair = (lane > 0u) && ((amL >> k) & 1u) && ((amL >> (k - 2)) & 1u);
                if (!leftpair)
                    unionk(par, s_par, (unsigned)i, (unsigned)(i - IMW));
            }
        }
        __syncthreads();

        // Phase B2: inter-strip boundary rows (first row of strips 1..15).
        // Up-neighbor activity from key level field (inactive slots keep level > l).
        if (w >= 1) {
#pragma unroll
            for (int k = 0; k < 2; ++k) {
                if (!((am >> k) & 1u)) continue;
                int i = (w << 10) + (k << 6) + (int)lane;
                if ((int)(s_par[i - IMW] >> 14) <= l) {
                    int col = (k << 6) + (int)lane;
                    bool lact = (lane > 0u) ? (((amL >> k) & 1u) != 0u)
                                            : (k == 1 ? (((am63 >> 0) & 1u) != 0u) : false);
                    bool leftpair = (col != 0) && lact && ((int)(s_par[i - 1 - IMW] >> 14) <= l);
                    if (!leftpair)
                        unionk(par, s_par, (unsigned)i, (unsigned)(i - IMW));
                }
            }
        }
        __syncthreads();

        // emit: root iff active && par[i]'s idx == i (keys are unique per idx)
#pragma unroll
        for (int k = 0; k < 16; ++k) {
            if (!((am >> k) & 1u)) continue;
            int i = (w << 10) + (k << 6) + (int)lane;
            if ((s_par[i] & IMASK) == (unsigned)i) atomicOr(&rm[i], 1u << l);
        }
        __syncthreads();
        if (tid == 0) flag_release(&flags[b]);
        return;
    }

    if (blk < 96) {
        // ================= death (r15-verbatim body) =================
        int img = blk - 88;
        uint8_t*  s_lvl  = (uint8_t*)smem;                               // 16384
        uint8_t*  s_rank = (uint8_t*)(smem + 16384);                     // 16384
        unsigned long long* s_bm = (unsigned long long*)(smem + 32768);  // 2048
        unsigned* s_keys = (unsigned*)(smem + 34816);                    // 1024
        unsigned* s_pc   = (unsigned*)(smem + 35840);                    // 1024
        unsigned* s_hist = (unsigned*)(smem + 36864);                    // 256
        uint8_t*  s_rtab = (uint8_t*)(smem + 37120);                     // 128
        unsigned* s_ctl  = (unsigned*)(smem + 37248);                    // 16

        if (tid < NLVL) flag_acquire(&flags[img * NLVL + tid]);
        __syncthreads();

        const uint8_t* lv = lvl_all + (size_t)img * NPIX;
        const unsigned* rmg = rootmask_all + (size_t)img * NPIX;
        int maxL = maxL_all[img];

        ((uint4*)s_lvl)[tid] = ((const uint4*)lv)[tid];
        if (tid < 64) s_hist[tid] = 0;
        if (tid < 256) { s_bm[tid] = 0ull; s_keys[tid] = 0xFFFFFFFFu; }
        // rank(d,b) = #(of 55 (dd,bb) pairs) with strictly larger f32 pers;
        // order-isomorphic to float ordering; equal floats share rank -> tie by idx.
        if (tid < NLVL * NLVL) {
            int d = tid / NLVL, bb0 = tid % NLVL;
            if (d > bb0) {
                float pers = (float)d / 10.0f - (float)bb0 / 10.0f;
                unsigned rk = 0;
                for (int dd = 1; dd <= 10; ++dd)
                    for (int bb = 0; bb < dd; ++bb) {
                        float pp = (float)dd / 10.0f - (float)bb / 10.0f;
                        rk += (pp > pers) ? 1u : 0u;
                    }
                s_rtab[d * NLVL + bb0] = (uint8_t)rk;
            }
        }
        __syncthreads();

        // pass 1: candidate iff root at birth level; death = first clear bit above b
        for (int i = tid; i < NPIX; i += 1024) {
            uint8_t r = 0xFF;
            int b = s_lvl[i];
            unsigned rmv = rmg[i];
            if ((rmv >> b) & 1u) {
                unsigned inv = (~rmv) >> (b + 1);
                int d = b + 1 + (__ffs(inv) - 1);
                d = min(d, maxL);
                if (d > b) { r = s_rtab[d * NLVL + b]; atomicAdd(&s_hist[r], 1u); }
            }
            s_rank[i] = r;
        }
        __syncthreads();

        if (tid == 0) {
            unsigned cum = 0, rstar = 63, cless = 0;
            for (int r = 0; r < 56; ++r) {
                if (cum + s_hist[r] >= 256u && rstar == 63u) { rstar = r; cless = cum; }
                cum += s_hist[r];
            }
            if (rstar == 63u) cless = cum;
            s_ctl[0] = rstar; s_ctl[1] = cless;
            s_ctl[2] = (rstar == 63u) ? 0u : (256u - cless);
            s_ctl[3] = 0;
        }
        __syncthreads();
        unsigned rstar = s_ctl[0], cless = s_ctl[1], mneed = s_ctl[2];

        // pass 2: compact rank<r*; bitmap for rank==r*
        for (int i = tid; i < NPIX; i += 1024) {
            unsigned r = s_rank[i];
            if (r == 0xFFu) continue;
            if (r < rstar) {
                unsigned pos = atomicAdd(&s_ctl[3], 1u);
                if (pos < 256u) s_keys[pos] = (r << 14) | (unsigned)i;
            } else if (r == rstar) {
                atomicOr(&s_bm[i >> 6], 1ull << (i & 63));
            }
        }
        __syncthreads();

        // bitonic sort 256 keys ascending == (rank asc, idx asc)
        for (unsigned kk = 2; kk <= 256; kk <<= 1) {
            for (unsigned j = kk >> 1; j > 0; j >>= 1) {
                if (tid < 256) {
                    unsigned i = (unsigned)tid, ixj = i ^ j;
                    if (ixj > i) {
                        unsigned x = s_keys[i], y = s_keys[ixj];
                        bool up = ((i & kk) == 0);
                        if ((x > y) == up) { s_keys[i] = y; s_keys[ixj] = x; }
                    }
                }
                __syncthreads();
            }
        }

        // bucket r*: popcount-prefix -> each member computes its slot
        if (tid < 256) s_pc[tid] = (unsigned)__popcll(s_bm[tid]);
        __syncthreads();
        for (int d = 1; d < 256; d <<= 1) {
            unsigned x = 0;
            if (tid < 256 && tid >= d) x = s_pc[tid - d];
            __syncthreads();
            if (tid < 256 && tid >= d) s_pc[tid] += x;
            __syncthreads();
        }
        for (int i = tid; i < NPIX; i += 1024) {
            if (s_rank[i] != rstar || rstar == 63u) continue;
            if (!((s_bm[i >> 6] >> (i & 63)) & 1ull)) continue;
            unsigned w = i >> 6;
            unsigned order = (w ? s_pc[w - 1] : 0u)
                           + (unsigned)__popcll(s_bm[w] & ((1ull << (i & 63)) - 1ull));
            if (order < mneed) s_keys[cless + order] = (rstar << 14) | (unsigned)i;
        }
        __syncthreads();

        for (int s = tid; s < 256; s += 1024) {
            unsigned key = s_keys[s];
            float p = 0.f, bv = 0.f, dv = 0.f;
            if (key != 0xFFFFFFFFu) {
                unsigned i = key & IMASK;
                int b = s_lvl[i];
                unsigned rmv = rmg[i];
                unsigned inv = (~rmv) >> (b + 1);
                int d = b + 1 + (__ffs(inv) - 1);
                d = min(d, maxL);
                bv = (float)b / 10.0f;
                dv = (float)d / 10.0f;
                p = dv - bv;
            }
            outP[img * 256 + s] = p;
            outB[img * 256 + s] = bv;
            outD[img * 256 + s] = dv;
        }
        __syncthreads();
        if (tid == 0) flag_release(&dflags[img]);
        return;
    }

    // ================= wdist (r15-verbatim body) =================
    {
        if (tid < 8) flag_acquire(&dflags[tid]);
        __syncthreads();

        float* part = (float*)smem;          // [16]
        float* dist = (float*)(smem + 64);   // [4]
        int s = tid >> 8;
        int slot = tid & 255;
        int mi = s * 256 + slot;
        int pi = (4 + s) * 256 + slot;
        float p1 = outP[mi], b1 = outB[mi], d1 = outD[mi];
        float p2 = outP[pi], b2 = outB[pi], d2 = outD[pi];
        bool h1 = p1 > 0.f, h2 = p2 > 0.f;
        float cost = 0.f;
        if (h1 && h2)      cost = (b1 - b2) * (b1 - b2) + (d1 - d2) * (d1 - d2);
        else if (h1)       cost = p1 * p1 * 0.5f;
        else if (h2)       cost = p2 * p2 * 0.5f;

        for (int off = 32; off > 0; off >>= 1) cost += __shfl_down(cost, off);
        int wv = tid >> 6;
        if (lane == 0u) part[wv] = cost;
        __syncthreads();
        if (tid < 4) {
            float sum = part[tid * 4] + part[tid * 4 + 1] + part[tid * 4 + 2] + part[tid * 4 + 3];
            dist[tid] = sqrtf(sum + 1e-12f);
        }
        __syncthreads();
        if (tid == 0)
            out[0] = 0.01f * (dist[0] + dist[1] + dist[2] + dist[3]) / 4.0f;
    }
}

// ws layout (bytes):
//   lvl   u8 [8][16384]         @ 0        (131072)
//   maxL  i32[8]                @ 131072   (32)
//   argmin u32[8]               @ 131104   (32)
//   rootmask u32[8][16384]      @ 131136   (524288)
//   outP/outB/outD f32[8][256]  @ 655424   (24576)
//   flags u32[88]               @ 680000   (352)
//   dflags u32[8]               @ 680352   (32)
extern "C" void kernel_launch(void* const* d_in, const int* in_sizes, int n_in,
                              void* d_out, int out_size, void* d_ws, size_t ws_size,
                              hipStream_t stream)
{
    const float* model_output = (const float*)d_in[0];
    const float* labels = (const float*)d_in[1];
    char* ws = (char*)d_ws;
    uint8_t* lvl = (uint8_t*)ws;
    int* maxL = (int*)(ws + 131072);
    unsigned* argmin = (unsigned*)(ws + 131104);
    unsigned* rootmask = (unsigned*)(ws + 131136);
    float* outP = (float*)(ws + 655424);
    float* outB = outP + NIMG * 256;
    float* outD = outB + NIMG * 256;
    unsigned* flags = (unsigned*)(ws + 680000);
    unsigned* dflags = (unsigned*)(ws + 680352);
    float* out = (float*)d_out;

    prep_kernel<<<NIMG, 1024, 0, stream>>>(model_output, labels, lvl, maxL, argmin, rootmask);
    ccl_death_wdist<<<97, 1024, 0, stream>>>(lvl, maxL, argmin, rootmask,
                                             outP, outB, outD, flags, dflags, out);
}